// Round 1
// baseline (3842.636 us; speedup 1.0000x reference)
//
#include <hip/hip_runtime.h>
#include <math.h>

// Problem constants (from the reference)
#define NUM_P 3
#define NUM_N 50000
#define NUM_C 5
#define NUM_F 68
#define NUM_E 150000
#define DIM_EF 64
#define DIM_NF 64
#define TWO_F 136
#define CF (NUM_C * NUM_F)   // 340

// ---------------------------------------------------------------------------
// Edge kernel: one 64-lane wave per edge.
//   h      = tanh(e_in @ ew1 + eb1)       (per class, lane = output feature)
//   logit  = h @ ew2 + eb2                (shfl-xor reduction)
//   w      = softmax_c(logit)
//   atomicAdd(aggr[dst], w[c] * x_j)
// ---------------------------------------------------------------------------
__global__ __launch_bounds__(256) void edge_kernel(
    const float* __restrict__ x,      // [P][N][C][F]
    const int*   __restrict__ ei,     // [P][2][E]
    const float* __restrict__ ew1,    // [P][C][2F][EF]
    const float* __restrict__ eb1,    // [P][C][EF]
    const float* __restrict__ ew2,    // [P][C][EF] (trailing 1 dropped)
    const float* __restrict__ eb2,    // [P][C]
    float*       __restrict__ aggr)   // [P][N][C][F]
{
    __shared__ float smem[4][NUM_C][TWO_F];

    const int wslot = threadIdx.x >> 6;
    const int lane  = threadIdx.x & 63;
    const int gw    = blockIdx.x * 4 + wslot;        // 0 .. P*E-1 (exact grid)
    const int p     = gw / NUM_E;
    const int e     = gw - p * NUM_E;

    const int src = ei[(p * 2 + 0) * NUM_E + e];
    const int dst = ei[(p * 2 + 1) * NUM_E + e];

    const float* xi = x + (p * NUM_N + dst) * CF;    // target (x_i)
    const float* xj = x + (p * NUM_N + src) * CF;    // source (x_j)

    float (*ein)[TWO_F] = smem[wslot];
    // gather: ein[c][0..67] = x_i[c], ein[c][68..135] = x_j[c]
    #pragma unroll
    for (int it = 0; it < 6; ++it) {
        int i = lane + 64 * it;
        if (i < CF) {
            int c = i / NUM_F;
            int f = i - c * NUM_F;
            ein[c][f]         = xi[i];
            ein[c][NUM_F + f] = xj[i];
        }
    }
    __syncthreads();

    float logits[NUM_C];
    #pragma unroll 1
    for (int c = 0; c < NUM_C; ++c) {
        const float* w1 = ew1 + (p * NUM_C + c) * TWO_F * DIM_EF;
        float acc = eb1[(p * NUM_C + c) * DIM_EF + lane];
        const float* er = ein[c];
        #pragma unroll 8
        for (int f = 0; f < TWO_F; ++f) {
            acc = fmaf(er[f], w1[f * DIM_EF + lane], acc);
        }
        float h    = tanhf(acc);
        float part = h * ew2[(p * NUM_C + c) * DIM_EF + lane];
        #pragma unroll
        for (int o = 32; o > 0; o >>= 1) part += __shfl_xor(part, o, 64);
        logits[c] = part + eb2[p * NUM_C + c];
    }

    // softmax over classes (wave-uniform after full butterfly)
    float m = logits[0];
    #pragma unroll
    for (int c = 1; c < NUM_C; ++c) m = fmaxf(m, logits[c]);
    float s = 0.f;
    float wts[NUM_C];
    #pragma unroll
    for (int c = 0; c < NUM_C; ++c) { wts[c] = __expf(logits[c] - m); s += wts[c]; }
    const float inv = 1.0f / s;

    float* ag = aggr + (p * NUM_N + dst) * CF;
    #pragma unroll
    for (int c = 0; c < NUM_C; ++c) {
        const float wv = wts[c] * inv;
        atomicAdd(&ag[c * NUM_F + lane], wv * ein[c][NUM_F + lane]);
        if (lane < NUM_F - 64) {   // features 64..67
            atomicAdd(&ag[c * NUM_F + 64 + lane], wv * ein[c][NUM_F + 64 + lane]);
        }
    }
}

// ---------------------------------------------------------------------------
// Node kernel: one 64-lane wave per node.
//   u_in = [x, aggr]  (C x 136)
//   h2   = tanh(u_in @ nw1 + nb1)   (lane = output feature)
//   out  = tanh(h2  @ nw2 + nb2)    (h2 broadcast via per-wave LDS)
// ---------------------------------------------------------------------------
__global__ __launch_bounds__(256) void node_kernel(
    const float* __restrict__ x,      // [P][N][C][F]
    const float* __restrict__ aggr,   // [P][N][C][F]
    const float* __restrict__ nw1,    // [P][C][2F][NF]
    const float* __restrict__ nb1,    // [P][C][NF]
    const float* __restrict__ nw2,    // [P][C][NF][NF]
    const float* __restrict__ nb2,    // [P][C][NF]
    float*       __restrict__ out)    // [P][N][C][NF]
{
    __shared__ float smem[4][NUM_C][TWO_F];
    __shared__ float hbuf[4][DIM_NF];

    const int wslot = threadIdx.x >> 6;
    const int lane  = threadIdx.x & 63;
    const int gw    = blockIdx.x * 4 + wslot;        // 0 .. P*N-1 (exact grid)
    const int p     = gw / NUM_N;
    const int n     = gw - p * NUM_N;

    const float* xr = x    + (p * NUM_N + n) * CF;
    const float* ar = aggr + (p * NUM_N + n) * CF;

    float (*uin)[TWO_F] = smem[wslot];
    #pragma unroll
    for (int it = 0; it < 6; ++it) {
        int i = lane + 64 * it;
        if (i < CF) {
            int c = i / NUM_F;
            int f = i - c * NUM_F;
            uin[c][f]         = xr[i];
            uin[c][NUM_F + f] = ar[i];
        }
    }
    __syncthreads();

    float* outp = out + (p * NUM_N + n) * (NUM_C * DIM_NF);

    #pragma unroll 1
    for (int c = 0; c < NUM_C; ++c) {
        // layer 1
        const float* w1 = nw1 + (p * NUM_C + c) * TWO_F * DIM_NF;
        float acc = nb1[(p * NUM_C + c) * DIM_NF + lane];
        const float* ur = uin[c];
        #pragma unroll 8
        for (int f = 0; f < TWO_F; ++f) {
            acc = fmaf(ur[f], w1[f * DIM_NF + lane], acc);
        }
        float h2 = tanhf(acc);
        hbuf[wslot][lane] = h2;   // wave-internal: hw lockstep + compiler waitcnt

        // layer 2
        const float* w2 = nw2 + (p * NUM_C + c) * DIM_NF * DIM_NF;
        float acc2 = nb2[(p * NUM_C + c) * DIM_NF + lane];
        #pragma unroll 8
        for (int f = 0; f < DIM_NF; ++f) {
            acc2 = fmaf(hbuf[wslot][f], w2[f * DIM_NF + lane], acc2);
        }
        outp[c * DIM_NF + lane] = tanhf(acc2);
    }
}

extern "C" void kernel_launch(void* const* d_in, const int* in_sizes, int n_in,
                              void* d_out, int out_size, void* d_ws, size_t ws_size,
                              hipStream_t stream)
{
    (void)in_sizes; (void)n_in; (void)out_size; (void)ws_size;

    const float* x   = (const float*)d_in[0];
    const int*   ei  = (const int*)  d_in[1];
    const float* ew1 = (const float*)d_in[2];
    const float* eb1 = (const float*)d_in[3];
    const float* ew2 = (const float*)d_in[4];
    const float* eb2 = (const float*)d_in[5];
    const float* nw1 = (const float*)d_in[6];
    const float* nb1 = (const float*)d_in[7];
    const float* nw2 = (const float*)d_in[8];
    const float* nb2 = (const float*)d_in[9];
    float*       out = (float*)d_out;

    float* aggr = (float*)d_ws;   // [P][N][C][F] = 204 MB scratch
    const size_t aggr_bytes = (size_t)NUM_P * NUM_N * NUM_C * NUM_F * sizeof(float);
    hipMemsetAsync(aggr, 0, aggr_bytes, stream);

    edge_kernel<<<(NUM_P * NUM_E) / 4, 256, 0, stream>>>(x, ei, ew1, eb1, ew2, eb2, aggr);
    node_kernel<<<(NUM_P * NUM_N) / 4, 256, 0, stream>>>(x, aggr, nw1, nb1, nw2, nb2, out);
}

// Round 2
// 1955.422 us; speedup vs baseline: 1.9651x; 1.9651x over previous
//
#include <hip/hip_runtime.h>
#include <math.h>

#define NUM_P 3
#define NUM_N 50000
#define NUM_C 5
#define NUM_F 68
#define NUM_E 150000
#define DIM_EF 64
#define DIM_NF 64
#define TWO_F 136
#define CF (NUM_C * NUM_F)          // 340
#define EBLK 586                    // ceil(E/256)
#define NBLK 196                    // ceil(N/256)

// tanh(x) = 1 - 2/(exp(2x)+1); exp via v_exp, rcp via v_rcp (1-ulp approx).
// Saturates correctly at +-1 for |x| large.
__device__ __forceinline__ float fast_tanh(float x) {
    float a = __expf(2.0f * x);                  // v_mul + v_exp
    float t = __builtin_amdgcn_rcpf(a + 1.0f);   // v_add + v_rcp
    return fmaf(-2.0f, t, 1.0f);                 // v_fma
}

// acc[o] += base[f] * wsec[f*64+o], f = 0..67.  base is per-lane (vector
// float4 loads, 1-deep prefetch); wsec is wave-uniform (scalar loads).
__device__ __forceinline__ void mlp68(const float* __restrict__ base,
                                      const float* __restrict__ wsec,
                                      float acc[DIM_EF])
{
    float4 ev = *(const float4*)(base);
    #pragma unroll 1
    for (int f4 = 0; f4 < 64; f4 += 4) {
        const float4 evn = *(const float4*)(base + f4 + 4);   // prefetch
        const float* wr = wsec + f4 * 64;
        #pragma unroll
        for (int ff = 0; ff < 4; ++ff) {
            const float e0 = (ff == 0) ? ev.x : (ff == 1) ? ev.y
                           : (ff == 2) ? ev.z : ev.w;
            #pragma unroll
            for (int o4 = 0; o4 < 64; o4 += 4) {
                const float4 wv = *(const float4*)(wr + ff * 64 + o4);
                acc[o4 + 0] = fmaf(e0, wv.x, acc[o4 + 0]);
                acc[o4 + 1] = fmaf(e0, wv.y, acc[o4 + 1]);
                acc[o4 + 2] = fmaf(e0, wv.z, acc[o4 + 2]);
                acc[o4 + 3] = fmaf(e0, wv.w, acc[o4 + 3]);
            }
        }
        ev = evn;
    }
    // tail f = 64..67
    const float* wr = wsec + 64 * 64;
    #pragma unroll
    for (int ff = 0; ff < 4; ++ff) {
        const float e0 = (ff == 0) ? ev.x : (ff == 1) ? ev.y
                       : (ff == 2) ? ev.z : ev.w;
        #pragma unroll
        for (int o4 = 0; o4 < 64; o4 += 4) {
            const float4 wv = *(const float4*)(wr + ff * 64 + o4);
            acc[o4 + 0] = fmaf(e0, wv.x, acc[o4 + 0]);
            acc[o4 + 1] = fmaf(e0, wv.y, acc[o4 + 1]);
            acc[o4 + 2] = fmaf(e0, wv.z, acc[o4 + 2]);
            acc[o4 + 3] = fmaf(e0, wv.w, acc[o4 + 3]);
        }
    }
}

// acc[o] += h[f] * w[f*64+o], f,o = 0..63. h per-lane registers (fully
// unrolled so indices stay static -> no scratch), w scalar-loaded.
__device__ __forceinline__ void mlp64(const float h[DIM_NF],
                                      const float* __restrict__ w,
                                      float acc[DIM_NF])
{
    #pragma unroll
    for (int f = 0; f < 64; ++f) {
        const float hf = h[f];
        const float* wr = w + f * 64;
        #pragma unroll
        for (int o4 = 0; o4 < 64; o4 += 4) {
            const float4 wv = *(const float4*)(wr + o4);
            acc[o4 + 0] = fmaf(hf, wv.x, acc[o4 + 0]);
            acc[o4 + 1] = fmaf(hf, wv.y, acc[o4 + 1]);
            acc[o4 + 2] = fmaf(hf, wv.z, acc[o4 + 2]);
            acc[o4 + 3] = fmaf(hf, wv.w, acc[o4 + 3]);
        }
    }
}

// ---------------------------------------------------------------------------
// E1: lane = edge. Computes softmax gate weights wout[P][C][E].
// Weights in SGPRs (wave-uniform addresses), inputs per-lane float4 gathers.
// ---------------------------------------------------------------------------
__global__ __launch_bounds__(256) void edge_mlp_kernel(
    const float* __restrict__ x,      // [P][N][C][F]
    const int*   __restrict__ ei,     // [P][2][E]
    const float* __restrict__ ew1,    // [P][C][2F][EF]
    const float* __restrict__ eb1,    // [P][C][EF]
    const float* __restrict__ ew2,    // [P][C][EF]
    const float* __restrict__ eb2,    // [P][C]
    float*       __restrict__ wout)   // [P][C][E]
{
    const int lane  = threadIdx.x & 63;
    const int wslot = threadIdx.x >> 6;
    const int p     = blockIdx.x / EBLK;
    const int blk   = blockIdx.x - p * EBLK;
    const int e     = blk * 256 + wslot * 64 + lane;
    const bool active = (e < NUM_E);
    const int ec    = active ? e : (NUM_E - 1);

    const int src = ei[(p * 2 + 0) * NUM_E + ec];
    const int dst = ei[(p * 2 + 1) * NUM_E + ec];
    const float* xi = x + ((size_t)p * NUM_N + dst) * CF;  // target
    const float* xj = x + ((size_t)p * NUM_N + src) * CF;  // source

    float logits[NUM_C];
    #pragma unroll 1
    for (int c = 0; c < NUM_C; ++c) {
        const float* w1 = ew1 + (size_t)(p * NUM_C + c) * TWO_F * DIM_EF;
        const float* b1 = eb1 + (p * NUM_C + c) * DIM_EF;
        float acc[DIM_EF];
        #pragma unroll
        for (int o4 = 0; o4 < 64; o4 += 4) {
            const float4 bv = *(const float4*)(b1 + o4);
            acc[o4] = bv.x; acc[o4 + 1] = bv.y; acc[o4 + 2] = bv.z; acc[o4 + 3] = bv.w;
        }
        mlp68(xi + c * NUM_F, w1, acc);
        mlp68(xj + c * NUM_F, w1 + NUM_F * DIM_EF, acc);

        const float* w2 = ew2 + (p * NUM_C + c) * DIM_EF;
        float lg = eb2[p * NUM_C + c];
        #pragma unroll
        for (int o = 0; o < 64; ++o) lg = fmaf(fast_tanh(acc[o]), w2[o], lg);
        logits[c] = lg;
    }

    float m = logits[0];
    #pragma unroll
    for (int c = 1; c < NUM_C; ++c) m = fmaxf(m, logits[c]);
    float s = 0.f, wts[NUM_C];
    #pragma unroll
    for (int c = 0; c < NUM_C; ++c) { wts[c] = __expf(logits[c] - m); s += wts[c]; }
    const float inv = __builtin_amdgcn_rcpf(s);

    if (active) {
        #pragma unroll
        for (int c = 0; c < NUM_C; ++c)
            wout[((size_t)p * NUM_C + c) * NUM_E + e] = wts[c] * inv;
    }
}

// ---------------------------------------------------------------------------
// E2: wave per edge. aggr[dst] += w[c] * x_j  (coalesced atomics).
// ---------------------------------------------------------------------------
__global__ __launch_bounds__(256) void edge_scatter_kernel(
    const float* __restrict__ x,
    const int*   __restrict__ ei,
    const float* __restrict__ wbuf,   // [P][C][E]
    float*       __restrict__ aggr)   // [P][N][C][F]
{
    const int wslot = threadIdx.x >> 6;
    const int lane  = threadIdx.x & 63;
    const int gw    = blockIdx.x * 4 + wslot;       // exact: P*E/4 blocks
    const int p     = gw / NUM_E;
    const int e     = gw - p * NUM_E;

    const int src = ei[(p * 2 + 0) * NUM_E + e];
    const int dst = ei[(p * 2 + 1) * NUM_E + e];
    const float* xj = x + ((size_t)p * NUM_N + src) * CF;
    float* ag       = aggr + ((size_t)p * NUM_N + dst) * CF;

    #pragma unroll
    for (int c = 0; c < NUM_C; ++c) {
        const float wv = wbuf[((size_t)p * NUM_C + c) * NUM_E + e]; // uniform
        atomicAdd(&ag[c * NUM_F + lane], wv * xj[c * NUM_F + lane]);
        if (lane < NUM_F - 64)
            atomicAdd(&ag[c * NUM_F + 64 + lane], wv * xj[c * NUM_F + 64 + lane]);
    }
}

// ---------------------------------------------------------------------------
// Node kernel: lane = node. Both layers per-lane, weights in SGPRs.
// ---------------------------------------------------------------------------
__global__ __launch_bounds__(256) void node_kernel(
    const float* __restrict__ x,      // [P][N][C][F]
    const float* __restrict__ aggr,   // [P][N][C][F]
    const float* __restrict__ nw1,    // [P][C][2F][NF]
    const float* __restrict__ nb1,    // [P][C][NF]
    const float* __restrict__ nw2,    // [P][C][NF][NF]
    const float* __restrict__ nb2,    // [P][C][NF]
    float*       __restrict__ out)    // [P][N][C][NF]
{
    const int lane  = threadIdx.x & 63;
    const int wslot = threadIdx.x >> 6;
    const int p     = blockIdx.x / NBLK;
    const int blk   = blockIdx.x - p * NBLK;
    const int n     = blk * 256 + wslot * 64 + lane;
    const bool active = (n < NUM_N);
    const int nc    = active ? n : (NUM_N - 1);

    const float* xr = x    + ((size_t)p * NUM_N + nc) * CF;
    const float* ar = aggr + ((size_t)p * NUM_N + nc) * CF;
    float* op       = out  + ((size_t)p * NUM_N + nc) * (NUM_C * DIM_NF);

    #pragma unroll 1
    for (int c = 0; c < NUM_C; ++c) {
        const float* w1 = nw1 + (size_t)(p * NUM_C + c) * TWO_F * DIM_NF;
        const float* b1 = nb1 + (p * NUM_C + c) * DIM_NF;
        float acc[DIM_NF];
        #pragma unroll
        for (int o4 = 0; o4 < 64; o4 += 4) {
            const float4 bv = *(const float4*)(b1 + o4);
            acc[o4] = bv.x; acc[o4 + 1] = bv.y; acc[o4 + 2] = bv.z; acc[o4 + 3] = bv.w;
        }
        mlp68(xr + c * NUM_F, w1, acc);
        mlp68(ar + c * NUM_F, w1 + NUM_F * DIM_NF, acc);

        float h2[DIM_NF];
        #pragma unroll
        for (int o = 0; o < 64; ++o) h2[o] = fast_tanh(acc[o]);

        const float* w2 = nw2 + (size_t)(p * NUM_C + c) * DIM_NF * DIM_NF;
        const float* b2 = nb2 + (p * NUM_C + c) * DIM_NF;
        float acc2[DIM_NF];
        #pragma unroll
        for (int o4 = 0; o4 < 64; o4 += 4) {
            const float4 bv = *(const float4*)(b2 + o4);
            acc2[o4] = bv.x; acc2[o4 + 1] = bv.y; acc2[o4 + 2] = bv.z; acc2[o4 + 3] = bv.w;
        }
        mlp64(h2, w2, acc2);

        if (active) {
            #pragma unroll
            for (int o4 = 0; o4 < 64; o4 += 4) {
                float4 ov;
                ov.x = fast_tanh(acc2[o4 + 0]);
                ov.y = fast_tanh(acc2[o4 + 1]);
                ov.z = fast_tanh(acc2[o4 + 2]);
                ov.w = fast_tanh(acc2[o4 + 3]);
                *(float4*)(op + c * DIM_NF + o4) = ov;
            }
        }
    }
}

extern "C" void kernel_launch(void* const* d_in, const int* in_sizes, int n_in,
                              void* d_out, int out_size, void* d_ws, size_t ws_size,
                              hipStream_t stream)
{
    (void)in_sizes; (void)n_in; (void)out_size;

    const float* x   = (const float*)d_in[0];
    const int*   ei  = (const int*)  d_in[1];
    const float* ew1 = (const float*)d_in[2];
    const float* eb1 = (const float*)d_in[3];
    const float* ew2 = (const float*)d_in[4];
    const float* eb2 = (const float*)d_in[5];
    const float* nw1 = (const float*)d_in[6];
    const float* nb1 = (const float*)d_in[7];
    const float* nw2 = (const float*)d_in[8];
    const float* nb2 = (const float*)d_in[9];
    float*       out = (float*)d_out;

    const size_t aggr_elems = (size_t)NUM_P * NUM_N * CF;
    const size_t w_elems    = (size_t)NUM_P * NUM_C * NUM_E;
    float* aggr = (float*)d_ws;
    float* wbuf = (ws_size >= (aggr_elems + w_elems) * sizeof(float))
                  ? (aggr + aggr_elems)
                  : out;   // fallback scratch: fully overwritten by node_kernel later

    hipMemsetAsync(aggr, 0, aggr_elems * sizeof(float), stream);

    edge_mlp_kernel<<<NUM_P * EBLK, 256, 0, stream>>>(x, ei, ew1, eb1, ew2, eb2, wbuf);
    edge_scatter_kernel<<<(NUM_P * NUM_E) / 4, 256, 0, stream>>>(x, ei, wbuf, aggr);
    node_kernel<<<NUM_P * NBLK, 256, 0, stream>>>(x, aggr, nw1, nb1, nw2, nb2, out);
}

// Round 4
// 1491.294 us; speedup vs baseline: 2.5767x; 1.3112x over previous
//
#include <hip/hip_runtime.h>
#include <hip/hip_fp16.h>
#include <math.h>

typedef unsigned int uint;
typedef __fp16 half2_t __attribute__((ext_vector_type(2)));

#define NUM_P 3
#define NUM_N 50000
#define NUM_C 5
#define NUM_F 68
#define NUM_E 150000
#define TWO_F 136
#define CF 340
#define PAIRS_NODE 170          // CF/2 packed half2 per node
#define EBLK 586                // ceil(E/256)
#define NBLK 196                // ceil(N/256)

// ---- sizes (uint/float units) ----
#define AH_T      ((size_t)NUM_P * NUM_N * PAIRS_NODE)   // 25,500,000
#define W1P_T     (NUM_P * NUM_C * 68 * 64)              // 65,280
#define W2P_T     (NUM_P * NUM_C * 32 * 64)              // 30,720
#define WBUF_T    ((size_t)NUM_P * NUM_C * NUM_E)        // 2,250,000

__device__ __forceinline__ float fast_tanh(float x) {
    float a = __expf(2.0f * x);
    float t = __builtin_amdgcn_rcpf(a + 1.0f);
    return fmaf(-2.0f, t, 1.0f);
}

__device__ __forceinline__ float dot2f(half2_t a, half2_t b, float c) {
#if __has_builtin(__builtin_amdgcn_fdot2)
    return __builtin_amdgcn_fdot2(a, b, c, false);
#else
    return fmaf((float)a[0], (float)b[0], fmaf((float)a[1], (float)b[1], c));
#endif
}

__device__ __forceinline__ uint pk2(float a, float b) {
    half2_t h = __builtin_amdgcn_cvt_pkrtz(a, b);
    return __builtin_bit_cast(uint, h);
}

// ---------------------------------------------------------------------------
// x fp32 -> packed half2 (8 floats -> uint4 per thread)
// ---------------------------------------------------------------------------
__global__ __launch_bounds__(256) void convert_x_kernel(
    const float4* __restrict__ x4, uint4* __restrict__ xh4, int total)
{
    int i = blockIdx.x * 256 + threadIdx.x;
    if (i >= total) return;
    float4 a = x4[2 * i], b = x4[2 * i + 1];
    uint4 o;
    o.x = pk2(a.x, a.y); o.y = pk2(a.z, a.w);
    o.z = pk2(b.x, b.y); o.w = pk2(b.z, b.w);
    xh4[i] = o;
}

// in: [T/64 pair-rows][2 rows][64 cols] fp32 -> out[i] = pk(in[2t][o], in[2t+1][o])
__global__ __launch_bounds__(256) void pack_pairs_kernel(
    const float* __restrict__ in, uint* __restrict__ outp, int total)
{
    int i = blockIdx.x * 256 + threadIdx.x;
    if (i >= total) return;
    int t = i >> 6, o = i & 63;
    outp[i] = pk2(in[t * 128 + o], in[t * 128 + 64 + o]);
}

// ---------------------------------------------------------------------------
// acc[o] += sum_r dot2(xpairs[r], wp[r*64+o]), r = 0..33 (one 68-feat side).
// xp: 34 uints per-lane (uint2-aligned); wp: wave-uniform (scalar loads).
// ---------------------------------------------------------------------------
__device__ __forceinline__ void dot_side(const uint* __restrict__ xp,
                                         const uint* __restrict__ wp,
                                         float acc[64])
{
    uint2 cur = *(const uint2*)(xp);
    #pragma unroll 1
    for (int j = 0; j < 17; ++j) {
        const int jn = (j < 16) ? (j + 1) : 16;
        const uint2 nxt = *(const uint2*)(xp + jn * 2);
        const half2_t a0 = __builtin_bit_cast(half2_t, cur.x);
        const half2_t a1 = __builtin_bit_cast(half2_t, cur.y);
        const uint* w0 = wp + (2 * j) * 64;
        #pragma unroll
        for (int o = 0; o < 64; ++o)
            acc[o] = dot2f(a0, __builtin_bit_cast(half2_t, w0[o]), acc[o]);
        const uint* w1 = w0 + 64;
        #pragma unroll
        for (int o = 0; o < 64; ++o)
            acc[o] = dot2f(a1, __builtin_bit_cast(half2_t, w1[o]), acc[o]);
        cur = nxt;
    }
}

// same but source is fp32 (68 floats, float4-aligned), packed inline
__device__ __forceinline__ void dot_side_f32(const float* __restrict__ xf,
                                             const uint* __restrict__ wp,
                                             float acc[64])
{
    float4 cur = *(const float4*)(xf);
    #pragma unroll 1
    for (int j = 0; j < 17; ++j) {
        const int jn = (j < 16) ? (j + 1) : 16;
        const float4 nxt = *(const float4*)(xf + jn * 4);
        const half2_t a0 = __builtin_amdgcn_cvt_pkrtz(cur.x, cur.y);
        const half2_t a1 = __builtin_amdgcn_cvt_pkrtz(cur.z, cur.w);
        const uint* w0 = wp + (2 * j) * 64;
        #pragma unroll
        for (int o = 0; o < 64; ++o)
            acc[o] = dot2f(a0, __builtin_bit_cast(half2_t, w0[o]), acc[o]);
        const uint* w1 = w0 + 64;
        #pragma unroll
        for (int o = 0; o < 64; ++o)
            acc[o] = dot2f(a1, __builtin_bit_cast(half2_t, w1[o]), acc[o]);
        cur = nxt;
    }
}

// ---------------------------------------------------------------------------
// E1: lane = edge. Softmax gate weights -> wout[P][C][E].
// ---------------------------------------------------------------------------
__global__ __launch_bounds__(256) void edge_mlp_kernel(
    const uint*  __restrict__ xh,     // [P][N][170]
    const int*   __restrict__ ei,     // [P][2][E]
    const uint*  __restrict__ ewp,    // [P][C][68][64] packed pairs
    const float* __restrict__ eb1,    // [P][C][64]
    const float* __restrict__ ew2,    // [P][C][64]
    const float* __restrict__ eb2,    // [P][C]
    float*       __restrict__ wout)   // [P][C][E]
{
    const int lane  = threadIdx.x & 63;
    const int wslot = threadIdx.x >> 6;
    const int p     = blockIdx.x / EBLK;
    const int blk   = blockIdx.x - p * EBLK;
    const int e     = blk * 256 + wslot * 64 + lane;
    const bool active = (e < NUM_E);
    const int ec    = active ? e : (NUM_E - 1);

    const int src = ei[(p * 2 + 0) * NUM_E + ec];
    const int dst = ei[(p * 2 + 1) * NUM_E + ec];
    const uint* xi = xh + (size_t)(p * NUM_N + dst) * PAIRS_NODE;   // target
    const uint* xj = xh + (size_t)(p * NUM_N + src) * PAIRS_NODE;   // source

    float logits[NUM_C];
    #pragma unroll 1
    for (int c = 0; c < NUM_C; ++c) {
        const int g = p * NUM_C + c;
        const float* b1 = eb1 + g * 64;
        float acc[64];
        #pragma unroll
        for (int o4 = 0; o4 < 64; o4 += 4) {
            const float4 bv = *(const float4*)(b1 + o4);
            acc[o4] = bv.x; acc[o4 + 1] = bv.y; acc[o4 + 2] = bv.z; acc[o4 + 3] = bv.w;
        }
        const uint* wg = ewp + (size_t)g * 68 * 64;
        dot_side(xi + c * 34, wg, acc);            // e_in[0:68]   = x_i
        dot_side(xj + c * 34, wg + 34 * 64, acc);  // e_in[68:136] = x_j

        const float* w2 = ew2 + g * 64;
        float lg = eb2[g];
        #pragma unroll
        for (int o = 0; o < 64; ++o) lg = fmaf(fast_tanh(acc[o]), w2[o], lg);
        logits[c] = lg;
    }

    float m = logits[0];
    #pragma unroll
    for (int c = 1; c < NUM_C; ++c) m = fmaxf(m, logits[c]);
    float s = 0.f, wts[NUM_C];
    #pragma unroll
    for (int c = 0; c < NUM_C; ++c) { wts[c] = __expf(logits[c] - m); s += wts[c]; }
    const float inv = __builtin_amdgcn_rcpf(s);

    if (active) {
        #pragma unroll
        for (int c = 0; c < NUM_C; ++c)
            wout[((size_t)p * NUM_C + c) * NUM_E + e] = wts[c] * inv;
    }
}

// ---------------------------------------------------------------------------
// E2: wave per edge; packed f16 atomics into aggr_h.
// ---------------------------------------------------------------------------
__global__ __launch_bounds__(256) void edge_scatter_kernel(
    const uint*  __restrict__ xh,
    const int*   __restrict__ ei,
    const float* __restrict__ wbuf,   // [P][C][E]
    uint*        __restrict__ aggr)   // [P][N][170] packed f16
{
    const int wslot = threadIdx.x >> 6;
    const int lane  = threadIdx.x & 63;
    const int gw    = blockIdx.x * 4 + wslot;       // exact: P*E/4 blocks
    const int p     = gw / NUM_E;
    const int e     = gw - p * NUM_E;

    const int src = ei[(p * 2 + 0) * NUM_E + e];
    const int dst = ei[(p * 2 + 1) * NUM_E + e];
    const uint* xp = xh  + (size_t)(p * NUM_N + src) * PAIRS_NODE;
    uint*       ap = aggr + (size_t)(p * NUM_N + dst) * PAIRS_NODE;

    uint wp0, wp1, wp2, wp3, wp4;
    {
        const size_t base = (size_t)p * NUM_C * NUM_E + e;
        float w0 = wbuf[base + 0 * NUM_E];
        float w1 = wbuf[base + 1 * NUM_E];
        float w2 = wbuf[base + 2 * NUM_E];
        float w3 = wbuf[base + 3 * NUM_E];
        float w4 = wbuf[base + 4 * NUM_E];
        wp0 = pk2(w0, w0); wp1 = pk2(w1, w1); wp2 = pk2(w2, w2);
        wp3 = pk2(w3, w3); wp4 = pk2(w4, w4);
    }

    #pragma unroll
    for (int k = 0; k < 3; ++k) {
        const int q = lane + 64 * k;
        if (q < PAIRS_NODE) {
            const int c = q / 34;
            const uint wu = (c == 0) ? wp0 : (c == 1) ? wp1 : (c == 2) ? wp2
                          : (c == 3) ? wp3 : wp4;
            half2_t m = __builtin_bit_cast(half2_t, wu) *
                        __builtin_bit_cast(half2_t, xp[q]);
            unsafeAtomicAdd((__half2*)(ap + q), __builtin_bit_cast(__half2, m));
        }
    }
}

// ---------------------------------------------------------------------------
// Node: lane = node. L1 via dot2 (x fp32 inline-packed + aggr_h native pairs),
// L2 via packed dot2 fully unrolled (static indices).
// ---------------------------------------------------------------------------
__global__ __launch_bounds__(256) void node_kernel(
    const float* __restrict__ x,      // [P][N][C][F] fp32
    const uint*  __restrict__ aggr,   // [P][N][170] packed f16
    const uint*  __restrict__ nwp,    // [P][C][68][64] packed pairs
    const uint*  __restrict__ n2p,    // [P][C][32][64] packed pairs
    const float* __restrict__ nb1,    // [P][C][64]
    const float* __restrict__ nb2,    // [P][C][64]
    float*       __restrict__ out)    // [P][N][C][64]
{
    const int lane  = threadIdx.x & 63;
    const int wslot = threadIdx.x >> 6;
    const int p     = blockIdx.x / NBLK;
    const int blk   = blockIdx.x - p * NBLK;
    const int n     = blk * 256 + wslot * 64 + lane;
    const bool active = (n < NUM_N);
    const int nc    = active ? n : (NUM_N - 1);

    const float* xr = x    + (size_t)(p * NUM_N + nc) * CF;
    const uint*  ar = aggr + (size_t)(p * NUM_N + nc) * PAIRS_NODE;
    float* op       = out  + (size_t)(p * NUM_N + nc) * (NUM_C * 64);

    #pragma unroll 1
    for (int c = 0; c < NUM_C; ++c) {
        const int g = p * NUM_C + c;
        const float* b1 = nb1 + g * 64;
        float acc[64];
        #pragma unroll
        for (int o4 = 0; o4 < 64; o4 += 4) {
            const float4 bv = *(const float4*)(b1 + o4);
            acc[o4] = bv.x; acc[o4 + 1] = bv.y; acc[o4 + 2] = bv.z; acc[o4 + 3] = bv.w;
        }
        const uint* wg = nwp + (size_t)g * 68 * 64;
        dot_side_f32(xr + c * NUM_F, wg, acc);      // u_in[0:68]   = x
        dot_side(ar + c * 34, wg + 34 * 64, acc);   // u_in[68:136] = aggr

        uint h2p[32];
        #pragma unroll
        for (int f2 = 0; f2 < 32; ++f2)
            h2p[f2] = pk2(fast_tanh(acc[2 * f2]), fast_tanh(acc[2 * f2 + 1]));

        const float* b2 = nb2 + g * 64;
        float acc2[64];
        #pragma unroll
        for (int o4 = 0; o4 < 64; o4 += 4) {
            const float4 bv = *(const float4*)(b2 + o4);
            acc2[o4] = bv.x; acc2[o4 + 1] = bv.y; acc2[o4 + 2] = bv.z; acc2[o4 + 3] = bv.w;
        }
        const uint* w2g = n2p + (size_t)g * 32 * 64;
        #pragma unroll
        for (int f2 = 0; f2 < 32; ++f2) {
            const half2_t hv = __builtin_bit_cast(half2_t, h2p[f2]);
            const uint* wr = w2g + f2 * 64;
            #pragma unroll
            for (int o = 0; o < 64; ++o)
                acc2[o] = dot2f(hv, __builtin_bit_cast(half2_t, wr[o]), acc2[o]);
        }

        if (active) {
            #pragma unroll
            for (int o4 = 0; o4 < 64; o4 += 4) {
                float4 ov;
                ov.x = fast_tanh(acc2[o4 + 0]);
                ov.y = fast_tanh(acc2[o4 + 1]);
                ov.z = fast_tanh(acc2[o4 + 2]);
                ov.w = fast_tanh(acc2[o4 + 3]);
                *(float4*)(op + c * 64 + o4) = ov;
            }
        }
    }
}

extern "C" void kernel_launch(void* const* d_in, const int* in_sizes, int n_in,
                              void* d_out, int out_size, void* d_ws, size_t ws_size,
                              hipStream_t stream)
{
    (void)in_sizes; (void)n_in; (void)out_size;

    const float* x   = (const float*)d_in[0];
    const int*   ei  = (const int*)  d_in[1];
    const float* ew1 = (const float*)d_in[2];
    const float* eb1 = (const float*)d_in[3];
    const float* ew2 = (const float*)d_in[4];
    const float* eb2 = (const float*)d_in[5];
    const float* nw1 = (const float*)d_in[6];
    const float* nb1 = (const float*)d_in[7];
    const float* nw2 = (const float*)d_in[8];
    const float* nb2 = (const float*)d_in[9];
    float*       out = (float*)d_out;

    // ws layout (uint units): [aggr_h | ewp | nwp | n2p | wbuf | (xh)]
    uint* ws      = (uint*)d_ws;
    uint* aggr_h  = ws;
    uint* ewp     = ws + AH_T;
    uint* nwp     = ewp + W1P_T;
    uint* n2p     = nwp + W1P_T;
    float* wbuf   = (float*)(n2p + W2P_T);
    const size_t o_xh = AH_T + 2 * (size_t)W1P_T + W2P_T + WBUF_T;
    const size_t need_all = (o_xh + AH_T) * sizeof(uint);
    // ws >= 204 MB is established (rounds 1-2 used it); xh falls back to d_out
    // (node_kernel reads only x/aggr_h/weights, then fully overwrites d_out).
    uint* xh = (ws_size >= need_all) ? (ws + o_xh) : (uint*)d_out;

    (void)hipMemsetAsync(aggr_h, 0, AH_T * sizeof(uint), stream);

    const int convT = (int)(AH_T / 4);                       // 6,375,000
    convert_x_kernel<<<(convT + 255) / 256, 256, 0, stream>>>(
        (const float4*)x, (uint4*)xh, convT);
    pack_pairs_kernel<<<(W1P_T + 255) / 256, 256, 0, stream>>>(ew1, ewp, W1P_T);
    pack_pairs_kernel<<<(W1P_T + 255) / 256, 256, 0, stream>>>(nw1, nwp, W1P_T);
    pack_pairs_kernel<<<(W2P_T + 255) / 256, 256, 0, stream>>>(nw2, n2p, W2P_T);

    edge_mlp_kernel<<<NUM_P * EBLK, 256, 0, stream>>>(xh, ei, ewp, eb1, ew2, eb2, wbuf);
    edge_scatter_kernel<<<(NUM_P * NUM_E) / 4, 256, 0, stream>>>(xh, ei, wbuf, aggr_h);
    node_kernel<<<NUM_P * NBLK, 256, 0, stream>>>(x, aggr_h, nwp, n2p, nb1, nb2, out);
}